// Round 1
// baseline (300.047 us; speedup 1.0000x reference)
//
#include <hip/hip_runtime.h>

// RoutingConv: N=50000 nodes, M=32 neighbors, D=128 dims, K=8 capsules (dd=16)
// u[n,k,:] = A * sum_j z[n,j,k,:] * (softmax_j(e)_j * sum_dd z[n,j,k,:]) + x[n,k,:]
// e_j = z_j . att[D:]   (e_self cancels in softmax over j)
//
// Mapping: one wave64 per node. Lane l owns dims {2l, 2l+1}; capsule = l/8.
// z kept in 64 VGPRs across both passes. Softmax normalization folded into a
// single final scale (linearity) so only one pass over stored z is needed
// after the logit pass.

#define N_NODES 50000
#define M_NBR   32
#define D_DIM   128
#define A_COEF  0.9f

__global__ __launch_bounds__(256) void routing_conv_kernel(
    const float* __restrict__ x,
    const float* __restrict__ att,
    const int*   __restrict__ nbr,
    float*       __restrict__ out)
{
    const int wave = threadIdx.x >> 6;
    const int lane = threadIdx.x & 63;
    const int node = blockIdx.x * 4 + wave;
    if (node >= N_NODES) return;

    // att second half (first half cancels in softmax); this lane's two weights
    const float2 a2 = *reinterpret_cast<const float2*>(att + D_DIM + lane * 2);
    const float2 x2 = *reinterpret_cast<const float2*>(x + (size_t)node * D_DIM + lane * 2);

    // neighbor indices: lanes 0..31 load, broadcast later via compile-time shfl
    int nidx = 0;
    if (lane < 32) nidx = nbr[node * M_NBR + lane];

    float zx[M_NBR], zy[M_NBR], e[M_NBR];
    float emax = -1e30f;

    // ---- pass 1: gather z rows (kept in regs) + per-neighbor logits ----
    #pragma unroll
    for (int j = 0; j < M_NBR; ++j) {
        const int nj = __shfl(nidx, j);          // wave-uniform
        float2 z = make_float2(0.f, 0.f);
        if (nj < N_NODES) {                      // index N == zero-pad row
            z = *reinterpret_cast<const float2*>(x + (size_t)nj * D_DIM + lane * 2);
        }
        zx[j] = z.x; zy[j] = z.y;

        float p = z.x * a2.x + z.y * a2.y;       // partial dot with att[D:]
        p += __shfl_xor(p, 1);
        p += __shfl_xor(p, 2);
        p += __shfl_xor(p, 4);
        p += __shfl_xor(p, 8);
        p += __shfl_xor(p, 16);
        p += __shfl_xor(p, 32);                  // full 64-lane sum -> e_j in all lanes
        e[j] = p;
        emax = fmaxf(emax, p);
    }

    // ---- pass 2: exp + capsule sums + weighted accumulation (unnormalized) ----
    float denom = 0.f, accx = 0.f, accy = 0.f;
    #pragma unroll
    for (int j = 0; j < M_NBR; ++j) {
        const float p = __expf(e[j] - emax);     // exp(e_j - max)
        denom += p;

        float t = zx[j] + zy[j];                 // capsule sum s_{j,k}: 16 elems = 8 lanes
        t += __shfl_xor(t, 1);
        t += __shfl_xor(t, 2);
        t += __shfl_xor(t, 4);                   // butterfly within aligned 8-lane group

        const float w = p * t;                   // (unnormalized attention) * s_jk
        accx += zx[j] * w;
        accy += zy[j] * w;
    }

    const float scale = A_COEF / denom;          // fold softmax denom + residual coef
    float2 o;
    o.x = scale * accx + x2.x;
    o.y = scale * accy + x2.y;
    *reinterpret_cast<float2*>(out + (size_t)node * D_DIM + lane * 2) = o;
}

extern "C" void kernel_launch(void* const* d_in, const int* in_sizes, int n_in,
                              void* d_out, int out_size, void* d_ws, size_t ws_size,
                              hipStream_t stream) {
    const float* x   = (const float*)d_in[0];
    const float* att = (const float*)d_in[1];
    const int*   nbr = (const int*)d_in[2];
    // d_in[3] = max_iter: unused (routing variable p never feeds back into u)
    float* out = (float*)d_out;

    const int nodes_per_block = 4;               // 4 waves/block, 1 node/wave
    const int grid = (N_NODES + nodes_per_block - 1) / nodes_per_block;  // 12500
    routing_conv_kernel<<<grid, 256, 0, stream>>>(x, att, nbr, out);
}

// Round 3
// 107.519 us; speedup vs baseline: 2.7906x; 2.7906x over previous
//
#include <hip/hip_runtime.h>

// RoutingConv: N=50000 nodes, M=32 neighbors, D=128 dims, K=8 capsules (dd=16)
// u[n,k,:] = A/denom * sum_j z[n,j,k,:] * (p_j * t_{j,k}) + x[n,k,:]
//   e_j = z_j . att[D:], p_j = exp(e_j - max), t_{j,k} = sum_dd z[n,j,k,:]
//
// One wave per node; lane l owns dims {2l,2l+1} (capsule = l>>3).
// All 32-neighbor reductions use multi-value transpose-reduce folds so the
// shuffle cost is ~1 DS op per value instead of log2(W) per value:
//   - logits: 5 fold stages (31 shfl) + xor32 -> lane l holds e_{l&31}
//   - capsule sums: 3 fold stages within 8-lane groups (28 shfl) -> 4 t/lane
// Neighbor indices load via SGPRs (readfirstlane'd node) - no broadcasts.

#define N_NODES 50000
#define M_NBR   32
#define D_DIM   128
#define A_COEF  0.9f

// One fold stage: NIN values/lane -> NIN/2 values/lane, each output summed
// over lane-pairs (lane ^ MASK). Adjacent pairing so that after folding with
// masks 1,2,4,... value index i maps to j = (NIN/2^stages)*i + (lane & span).
template<int MASK, int NIN>
__device__ __forceinline__ void fold_stage(const float* in, float* out, int lane) {
    const bool hi = (lane & MASK) != 0;
    #pragma unroll
    for (int i = 0; i < NIN / 2; ++i) {
        const float a = in[2 * i], b = in[2 * i + 1];
        const float send = hi ? a : b;         // ship the half we don't keep
        const float recv = __shfl_xor(send, MASK);
        const float keep = hi ? b : a;
        out[i] = keep + recv;
    }
}

__global__ __launch_bounds__(256) void routing_conv_kernel(
    const float* __restrict__ x,
    const float* __restrict__ att,
    const int*   __restrict__ nbr,
    float*       __restrict__ out)
{
    const int lane = threadIdx.x & 63;
    // wave-uniform node id in an SGPR -> scalar index loads + scalar addresses
    const int node = __builtin_amdgcn_readfirstlane(blockIdx.x * 4 + (threadIdx.x >> 6));

    const float2 a2 = *reinterpret_cast<const float2*>(att + D_DIM + lane * 2);
    const float2 x2 = *reinterpret_cast<const float2*>(x + (size_t)node * D_DIM + lane * 2);

    // neighbor indices: uniform address -> s_load_dwordx16 x2
    const int* nrow = nbr + node * M_NBR;
    int idx[M_NBR];
    #pragma unroll
    for (int j = 0; j < M_NBR; ++j) idx[j] = nrow[j];

    // ---- gather all 32 rows into registers (independent, overlap fully) ----
    float zx[M_NBR], zy[M_NBR];
    #pragma unroll
    for (int j = 0; j < M_NBR; ++j) {
        const int nj = idx[j];
        const bool valid = (nj < N_NODES);            // index N == zero-pad row
        const float2 z = *reinterpret_cast<const float2*>(
            x + (size_t)(valid ? nj : 0) * D_DIM + lane * 2);
        zx[j] = valid ? z.x : 0.f;
        zy[j] = valid ? z.y : 0.f;
    }

    // ---- logits: per-lane partials, then transpose-reduce ----
    float q[M_NBR];
    #pragma unroll
    for (int j = 0; j < M_NBR; ++j) q[j] = zx[j] * a2.x + zy[j] * a2.y;

    float r16[16], r8[8], r4[4], r2[2], r1[1];
    fold_stage<1, 32>(q, r16, lane);
    fold_stage<2, 16>(r16, r8, lane);
    fold_stage<4, 8>(r8, r4, lane);
    fold_stage<8, 4>(r4, r2, lane);
    fold_stage<16, 2>(r2, r1, lane);
    // r1[0] = sum over this 32-lane half for j = lane&31; add the other half
    const float e = r1[0] + __shfl_xor(r1[0], 32);    // lane l holds e_{l&31}

    // ---- softmax pieces over the 32 distributed logits (per 32-lane half) --
    float mx = e;
    mx = fmaxf(mx, __shfl_xor(mx, 1));
    mx = fmaxf(mx, __shfl_xor(mx, 2));
    mx = fmaxf(mx, __shfl_xor(mx, 4));
    mx = fmaxf(mx, __shfl_xor(mx, 8));
    mx = fmaxf(mx, __shfl_xor(mx, 16));
    const float p = __expf(e - mx);                   // ONE exp per lane
    float denom = p;
    denom += __shfl_xor(denom, 1);
    denom += __shfl_xor(denom, 2);
    denom += __shfl_xor(denom, 4);
    denom += __shfl_xor(denom, 8);
    denom += __shfl_xor(denom, 16);

    // ---- capsule sums t_{j,k}: fold within 8-lane groups ----
    float s[M_NBR];
    #pragma unroll
    for (int j = 0; j < M_NBR; ++j) s[j] = zx[j] + zy[j];
    float t16[16], t8[8], t4[4];
    fold_stage<1, 32>(s, t16, lane);
    fold_stage<2, 16>(t16, t8, lane);
    fold_stage<4, 8>(t8, t4, lane);
    // t4[i] = t_{8i+(lane&7), lane>>3}

    // ---- w_{j,k} = p_j * t_{j,k}, held where t lives ----
    float w[4];
    #pragma unroll
    for (int i = 0; i < 4; ++i)
        w[i] = __shfl(p, 8 * i + (lane & 7)) * t4[i];

    // ---- accumulate: lane needs w_{j, lane>>3} = w[j>>3] of lane (l&56)|(j&7)
    const int wsrc = lane & 56;
    float accx = 0.f, accy = 0.f;
    #pragma unroll
    for (int j = 0; j < M_NBR; ++j) {
        const float wjk = __shfl(w[j >> 3], wsrc | (j & 7));
        accx = fmaf(zx[j], wjk, accx);
        accy = fmaf(zy[j], wjk, accy);
    }

    const float scale = A_COEF / denom;               // fold softmax + residual
    float2 o;
    o.x = fmaf(scale, accx, x2.x);
    o.y = fmaf(scale, accy, x2.y);
    *reinterpret_cast<float2*>(out + (size_t)node * D_DIM + lane * 2) = o;
}

extern "C" void kernel_launch(void* const* d_in, const int* in_sizes, int n_in,
                              void* d_out, int out_size, void* d_ws, size_t ws_size,
                              hipStream_t stream) {
    const float* x   = (const float*)d_in[0];
    const float* att = (const float*)d_in[1];
    const int*   nbr = (const int*)d_in[2];
    // d_in[3] = max_iter: unused (routing variable never feeds back into u)
    float* out = (float*)d_out;

    const int grid = N_NODES / 4;                     // 4 waves/block, 1 node/wave
    routing_conv_kernel<<<grid, 256, 0, stream>>>(x, att, nbr, out);
}